// Round 18
// baseline (222.555 us; speedup 1.0000x reference)
//
#include <hip/hip_runtime.h>

#define DD 128
#define NC 10
#define NT 15
#define NCT 150
#define NCOLS 450
#define BTRAIN 100000
#define BTEST 100000
#define GROWS 70050   // 150 * 467 needed param rows
#define NGRP 38       // ceil(150/4) ct-groups of 4 (k=32 each)

typedef __attribute__((ext_vector_type(8))) __bf16 bf16x8;
typedef __attribute__((ext_vector_type(4))) float f32x4;
typedef __attribute__((ext_vector_type(8))) unsigned short u16x8;

static __device__ __forceinline__ unsigned short f2bf(float f) {
  unsigned int u = __builtin_bit_cast(unsigned int, f);
  u = (u + 0x7FFFu + ((u >> 16) & 1u)) >> 16;
  return (unsigned short)u;
}

// ---------- K1: column partial sums of X_train (512 blocks) ----------
__global__ void __launch_bounds__(256) k_colsum(const float* __restrict__ X, float* __restrict__ partial) {
  int tid = threadIdx.x;
  int gid = blockIdx.x * 256 + tid;
  int stride = gridDim.x * 256;
  float sx = 0.f, sy = 0.f, sz = 0.f, sw = 0.f;
  const float4* Xv = (const float4*)X;
  for (int i = gid; i < BTRAIN * 32; i += stride) {
    float4 v = Xv[i];
    sx += v.x; sy += v.y; sz += v.z; sw += v.w;
  }
  __shared__ float red[256][4];
  red[tid][0] = sx; red[tid][1] = sy; red[tid][2] = sz; red[tid][3] = sw;
  __syncthreads();
  for (int off = 128; off >= 32; off >>= 1) {
    if (tid < off) {
      red[tid][0] += red[tid + off][0];
      red[tid][1] += red[tid + off][1];
      red[tid][2] += red[tid + off][2];
      red[tid][3] += red[tid + off][3];
    }
    __syncthreads();
  }
  if (tid < 32) {
#pragma unroll
    for (int i = 0; i < 4; ++i)
      partial[blockIdx.x * 128 + tid * 4 + i] = red[tid][i];
  }
}

// ---------- K2: redundant {mean + L1 + LN1} per block, then 4 coalesced z2 rows ----------
__global__ void __launch_bounds__(256) k_z2(const float* __restrict__ partial,
                                            const float* __restrict__ W1, const float* __restrict__ b1,
                                            const float* __restrict__ g1, const float* __restrict__ bb1,
                                            const float* __restrict__ W2, const float* __restrict__ b2,
                                            float* __restrict__ z2g) {
  __shared__ float mS[128];
  __shared__ float redS[256];
  __shared__ float z1S[512];
  __shared__ float h1S[512];
  int tid = threadIdx.x;
  {
    int c = tid & 127, h = tid >> 7;
    float s = 0.0f;
    const float* pp = partial + (size_t)(h * 256) * 128 + c;
    for (int k = 0; k < 256; ++k) s += pp[k * 128];
    redS[tid] = s;
    __syncthreads();
    if (tid < 128) mS[tid] = (redS[tid] + redS[tid + 128]) * (1.0f / BTRAIN);
    __syncthreads();
  }
  for (int r = tid; r < 512; r += 256) {
    const float4* w = (const float4*)(W1 + (size_t)r * DD);
    float z = b1[r];
#pragma unroll
    for (int j = 0; j < 32; ++j) {
      float4 wv = w[j];
      z += wv.x * mS[4 * j] + wv.y * mS[4 * j + 1] + wv.z * mS[4 * j + 2] + wv.w * mS[4 * j + 3];
    }
    z1S[r] = z;
  }
  __syncthreads();
  {
    float a = z1S[tid], b = z1S[tid + 256];
    redS[tid] = a + b; __syncthreads();
    for (int off = 128; off > 0; off >>= 1) { if (tid < off) redS[tid] += redS[tid + off]; __syncthreads(); }
    float m = redS[0] * (1.0f / 512.0f); __syncthreads();
    float da = a - m, db = b - m;
    redS[tid] = da * da + db * db; __syncthreads();
    for (int off = 128; off > 0; off >>= 1) { if (tid < off) redS[tid] += redS[tid + off]; __syncthreads(); }
    float rs = rsqrtf(redS[0] * (1.0f / 512.0f) + 1e-5f); __syncthreads();
    h1S[tid] = fmaxf(da * rs * g1[tid] + bb1[tid], 0.0f);
    h1S[tid + 256] = fmaxf(db * rs * g1[tid + 256] + bb1[tid + 256], 0.0f);
  }
  __syncthreads();
  {
    int wv = tid >> 6, lane = tid & 63;
    int r = blockIdx.x * 4 + wv;
    const float4* wr = (const float4*)(W2 + (size_t)r * 512) + lane * 2;
    const float4* xv = (const float4*)h1S + lane * 2;
    float4 a0 = wr[0], a1 = wr[1], x0 = xv[0], x1 = xv[1];
    float s = a0.x * x0.x + a0.y * x0.y + a0.z * x0.z + a0.w * x0.w
            + a1.x * x1.x + a1.y * x1.y + a1.z * x1.z + a1.w * x1.w;
#pragma unroll
    for (int off = 32; off > 0; off >>= 1) s += __shfl_down(s, off);
    if (lane == 0) z2g[r] = s + b2[r];
  }
}

// ---------- K3: redundant LN2 per block, then 16 coalesced hh rows ----------
__global__ void __launch_bounds__(256) k_hh(const float* __restrict__ z2g,
                                            const float* __restrict__ g2, const float* __restrict__ bb2,
                                            const float* __restrict__ hW1, const float* __restrict__ hb1,
                                            float* __restrict__ hh) {
  __shared__ float redS[256];
  __shared__ float h2S[512];
  int tid = threadIdx.x;
  {
    float a = z2g[tid], b = z2g[tid + 256];
    redS[tid] = a + b; __syncthreads();
    for (int off = 128; off > 0; off >>= 1) { if (tid < off) redS[tid] += redS[tid + off]; __syncthreads(); }
    float m = redS[0] * (1.0f / 512.0f); __syncthreads();
    float da = a - m, db = b - m;
    redS[tid] = da * da + db * db; __syncthreads();
    for (int off = 128; off > 0; off >>= 1) { if (tid < off) redS[tid] += redS[tid + off]; __syncthreads(); }
    float rs = rsqrtf(redS[0] * (1.0f / 512.0f) + 1e-5f); __syncthreads();
    h2S[tid] = fmaxf(da * rs * g2[tid] + bb2[tid], 0.0f);
    h2S[tid + 256] = fmaxf(db * rs * g2[tid + 256] + bb2[tid + 256], 0.0f);
  }
  __syncthreads();
  int wv = tid >> 6, lane = tid & 63;
  const float4* xv = (const float4*)h2S + lane * 2;
  float4 x0 = xv[0], x1 = xv[1];
  float4 a[4][2];
  int r0 = blockIdx.x * 16 + wv * 4;
#pragma unroll
  for (int i = 0; i < 4; ++i) {
    const float4* wr = (const float4*)(hW1 + (size_t)(r0 + i) * 512) + lane * 2;
    a[i][0] = wr[0];
    a[i][1] = wr[1];
  }
#pragma unroll
  for (int i = 0; i < 4; ++i) {
    float s = a[i][0].x * x0.x + a[i][0].y * x0.y + a[i][0].z * x0.z + a[i][0].w * x0.w
            + a[i][1].x * x1.x + a[i][1].y * x1.y + a[i][1].z * x1.z + a[i][1].w * x1.w;
#pragma unroll
    for (int off = 32; off > 0; off >>= 1) s += __shfl_down(s, off);
    if (lane == 0) hh[r0 + i] = fmaxf(s + hb1[r0 + i], 0.0f);
  }
}

// ---------- K4: gather-matvec of needed head_W2 rows, 8 rows/wave ----------
__global__ void __launch_bounds__(256) k_params(const float* __restrict__ W2, const float* __restrict__ hh,
                                                const float* __restrict__ b2, unsigned short* __restrict__ Wb,
                                                float* __restrict__ sb, float* __restrict__ leaf) {
  int wv = threadIdx.x >> 6, lane = threadIdx.x & 63;
  int base = (blockIdx.x * 4 + wv) * 8;
  if (base >= GROWS) return;
  float4 a[8][2];
  size_t rowoff[8];
  int ctArr[8], wArr[8], cArr[8];
#pragma unroll
  for (int i = 0; i < 8; ++i) {
    int R = base + i;
    if (R >= GROWS) R = GROWS - 1;  // duplicate tail row: identical value stores, benign
    int ctIdx = R / 467;
    int w = R - ctIdx * 467;
    int c = ctIdx / 15;
    int t = ctIdx - c * 15;
    int p;
    if (w < 384) p = t * 983 + w;
    else if (w < 387) p = t * 983 + 896 + (w - 384);
    else p = t * 983 + 903 + (w - 387);
    rowoff[i] = (size_t)c * 14745 + p;
    ctArr[i] = ctIdx; wArr[i] = w; cArr[i] = c;
    const float4* wr = (const float4*)(W2 + rowoff[i] * 512) + lane * 2;
    a[i][0] = wr[0];
    a[i][1] = wr[1];
  }
#pragma unroll
  for (int i = 0; i < 8; ++i) {
    const float4* xv = (const float4*)(hh + cArr[i] * 512) + lane * 2;
    float4 x0 = xv[0], x1 = xv[1];
    float s = a[i][0].x * x0.x + a[i][0].y * x0.y + a[i][0].z * x0.z + a[i][0].w * x0.w
            + a[i][1].x * x1.x + a[i][1].y * x1.y + a[i][1].z * x1.z + a[i][1].w * x1.w;
#pragma unroll
    for (int off = 32; off > 0; off >>= 1) s += __shfl_down(s, off);
    if (lane == 0) {
      s += b2[rowoff[i]];
      int w = wArr[i], ctIdx = ctArr[i];
      if (w < 384) {
        int ii = w >> 7, d = w & 127;
        Wb[(size_t)(ctIdx * 3 + ii) * DD + d] = f2bf(s);
      } else if (w < 387) {
        sb[ctIdx * 3 + (w - 384)] = s;
      } else {
        leaf[ctIdx * 80 + (w - 387)] = s;
      }
    }
  }
}

// ---------- K5: TOB = softmax(leaf)*wt/C laid out as mfma B-fragments ----------
__global__ void k_tob(const float* __restrict__ leaf, const float* __restrict__ tw, unsigned short* __restrict__ TOB) {
  int g = blockIdx.x;          // 0..37
  int lane = threadIdx.x;      // 0..63
  int ct = g * 4 + (lane >> 4);
  int cls = lane & 15;
  float mx = tw[0];
  for (int i = 1; i < 15; ++i) mx = fmaxf(mx, tw[i]);
  float wsum = 0.0f;
  for (int i = 0; i < 15; ++i) wsum += __expf(tw[i] - mx);
  u16x8 o;
#pragma unroll
  for (int j = 0; j < 8; ++j) {
    float v = 0.0f;
    if (ct < NCT && cls < NC) {
      float wt = __expf(tw[ct % 15] - mx) / wsum;
      const float* lr = leaf + ct * 80 + j * 10;
      float m2 = lr[0];
#pragma unroll
      for (int k = 1; k < 10; ++k) m2 = fmaxf(m2, lr[k]);
      float es = 0.0f;
#pragma unroll
      for (int k = 0; k < 10; ++k) es += __expf(lr[k] - m2);
      v = __expf(lr[cls] - m2) / es * wt * (1.0f / (float)NC);
    }
    o[j] = f2bf(v);
  }
  *(u16x8*)&TOB[((size_t)g * 64 + lane) * 8] = o;
}

// ---------- K6: fused routes GEMM + sigmoid + MFMA tree-combine ----------
__global__ void __launch_bounds__(256) k_fused(const float* __restrict__ X, const unsigned short* __restrict__ Wb,
                                               const float* __restrict__ sb, const unsigned short* __restrict__ TOB,
                                               float* __restrict__ out) {
  __shared__ union {
    unsigned short Xs[64][152];   // 19456 B; stride 304 B = 76 dw -> conflict-free b128
    _Float16 Rs[64][242];         // 30976 B; stride 484 B = 121 dw (odd) -> conflict-free col reads
  } sU;
  int tid = threadIdx.x;
  int b0 = blockIdx.x * 64;
  // ---- phase A: stage X tile as bf16 (compiler emits v_cvt_pk_bf16_f32) ----
  {
    int row = tid >> 2, seg = tid & 3;
    int gb = b0 + row;
    const float4* xr = (const float4*)(X + (size_t)gb * DD) + seg * 8;
#pragma unroll
    for (int j2 = 0; j2 < 4; ++j2) {
      bf16x8 u;
      if (gb < BTEST) {
        float4 va = xr[2 * j2], vb = xr[2 * j2 + 1];
        u[0] = (__bf16)va.x; u[1] = (__bf16)va.y; u[2] = (__bf16)va.z; u[3] = (__bf16)va.w;
        u[4] = (__bf16)vb.x; u[5] = (__bf16)vb.y; u[6] = (__bf16)vb.z; u[7] = (__bf16)vb.w;
      } else {
#pragma unroll
        for (int j = 0; j < 8; ++j) u[j] = (__bf16)0.0f;
      }
      *(u16x8*)&sU.Xs[row][seg * 32 + j2 * 8] = __builtin_bit_cast(u16x8, u);
    }
  }
  __syncthreads();
  // ---- A-fragments (X) to registers; Xs dead afterwards ----
  int wv = tid >> 6, lane = tid & 63;
  int m = lane & 15, g = lane >> 4;
  bf16x8 A[4][4];
#pragma unroll
  for (int rt = 0; rt < 4; ++rt)
#pragma unroll
    for (int ks = 0; ks < 4; ++ks)
      A[rt][ks] = __builtin_bit_cast(bf16x8, *(const u16x8*)&sU.Xs[rt * 16 + m][ks * 32 + g * 8]);
  __syncthreads();
  f32x4 accA = 0.0f, accB = 0.0f;
  int pl = wv * 16 + m;            // this wave's point row in Rs for phase C
#pragma unroll
  for (int pass = 0; pass < 2; ++pass) {
    int passBase = pass ? 240 : 0;
    // ---- phase B: MFMA routes tiles + sigmoid into Rs (Wb prefetched) ----
    {
      int tstart, tcnt;
      if (pass == 0) { tstart = wv * 4; tcnt = (wv == 3) ? 3 : 4; }
      else { tstart = 15 + ((wv < 2) ? wv * 4 : (8 + (wv - 2) * 3)); tcnt = (wv < 2) ? 4 : 3; }
      int col = tstart * 16 + m;
      u16x8 Bv[4];
#pragma unroll
      for (int ks = 0; ks < 4; ++ks)
        Bv[ks] = *(const u16x8*)&Wb[(size_t)col * DD + ks * 32 + g * 8];
      float sbv = sb[col];
      for (int it = 0; it < tcnt; ++it) {
        int pc = (it + 1 < tcnt) ? (col + 16) : col;  // clamped prefetch
        u16x8 Bn[4];
#pragma unroll
        for (int ks = 0; ks < 4; ++ks)
          Bn[ks] = *(const u16x8*)&Wb[(size_t)pc * DD + ks * 32 + g * 8];
        float sbn = sb[pc];
        f32x4 acc[4];
#pragma unroll
        for (int rt = 0; rt < 4; ++rt) acc[rt] = 0.0f;
#pragma unroll
        for (int ks = 0; ks < 4; ++ks) {
          bf16x8 Bf = __builtin_bit_cast(bf16x8, Bv[ks]);
#pragma unroll
          for (int rt = 0; rt < 4; ++rt)
            acc[rt] = __builtin_amdgcn_mfma_f32_16x16x32_bf16(A[rt][ks], Bf, acc[rt], 0, 0, 0);
        }
        int colLocal = col - passBase;
#pragma unroll
        for (int rt = 0; rt < 4; ++rt)
#pragma unroll
          for (int r = 0; r < 4; ++r) {
            float pre = acc[rt][r] + sbv;
            float e = __expf(-pre);
            float sg = __builtin_amdgcn_rcpf(1.0f + e);
            sU.Rs[rt * 16 + g * 4 + r][colLocal] = (_Float16)sg;
          }
#pragma unroll
        for (int ks = 0; ks < 4; ++ks) Bv[ks] = Bn[ks];
        sbv = sbn;
        col += 16;
      }
    }
    __syncthreads();
    // ---- phase C: MFMA tree-combine, 4-group load batching (MLP vs latency).
    //      ct >= NCT needs no mask: TOB B-fragment is exactly 0 there. ----
    {
      int gbase = pass ? 20 : 0;
      int gn = pass ? 18 : 20;
      int ctl = g;  // lane>>4
      int nch = gn >> 2;  // full chunks of 4 (pass0: 5, pass1: 4)
      for (int ch = 0; ch < nch; ++ch) {
        int g0 = gbase + ch * 4;
        u16x8 bvs[4];
        _Float16 r0s[4], r1s[4], r2s[4];
#pragma unroll
        for (int u = 0; u < 4; ++u) {
          int gAbs = g0 + u;
          int cb = 3 * (gAbs * 4 + ctl) - passBase;
          r0s[u] = sU.Rs[pl][cb + 0];
          r1s[u] = sU.Rs[pl][cb + 1];
          r2s[u] = sU.Rs[pl][cb + 2];
          bvs[u] = *(const u16x8*)&TOB[((size_t)gAbs * 64 + lane) * 8];
        }
#pragma unroll
        for (int u = 0; u < 4; ++u) {
          float l0 = (float)r0s[u], l1 = (float)r1s[u], l2 = (float)r2s[u];
          float n0 = 1.0f - l0, n1 = 1.0f - l1, n2 = 1.0f - l2;
          float p00 = l1 * l0, p01 = l1 * n0, p10 = n1 * l0, p11 = n1 * n0;
          bf16x8 av;
          av[0] = (__bf16)(l2 * p00); av[1] = (__bf16)(l2 * p01);
          av[2] = (__bf16)(l2 * p10); av[3] = (__bf16)(l2 * p11);
          av[4] = (__bf16)(n2 * p00); av[5] = (__bf16)(n2 * p01);
          av[6] = (__bf16)(n2 * p10); av[7] = (__bf16)(n2 * p11);
          if (u & 1)
            accB = __builtin_amdgcn_mfma_f32_16x16x32_bf16(av, __builtin_bit_cast(bf16x8, bvs[u]), accB, 0, 0, 0);
          else
            accA = __builtin_amdgcn_mfma_f32_16x16x32_bf16(av, __builtin_bit_cast(bf16x8, bvs[u]), accA, 0, 0, 0);
        }
      }
      if (gn & 3) {  // pass1 tail: 2 groups
        int g0 = gbase + nch * 4;
        u16x8 bvs[2];
        _Float16 r0s[2], r1s[2], r2s[2];
#pragma unroll
        for (int u = 0; u < 2; ++u) {
          int gAbs = g0 + u;
          int cb = 3 * (gAbs * 4 + ctl) - passBase;
          r0s[u] = sU.Rs[pl][cb + 0];
          r1s[u] = sU.Rs[pl][cb + 1];
          r2s[u] = sU.Rs[pl][cb + 2];
          bvs[u] = *(const u16x8*)&TOB[((size_t)gAbs * 64 + lane) * 8];
        }
#pragma unroll
        for (int u = 0; u < 2; ++u) {
          float l0 = (float)r0s[u], l1 = (float)r1s[u], l2 = (float)r2s[u];
          float n0 = 1.0f - l0, n1 = 1.0f - l1, n2 = 1.0f - l2;
          float p00 = l1 * l0, p01 = l1 * n0, p10 = n1 * l0, p11 = n1 * n0;
          bf16x8 av;
          av[0] = (__bf16)(l2 * p00); av[1] = (__bf16)(l2 * p01);
          av[2] = (__bf16)(l2 * p10); av[3] = (__bf16)(l2 * p11);
          av[4] = (__bf16)(n2 * p00); av[5] = (__bf16)(n2 * p01);
          av[6] = (__bf16)(n2 * p10); av[7] = (__bf16)(n2 * p11);
          if (u & 1)
            accB = __builtin_amdgcn_mfma_f32_16x16x32_bf16(av, __builtin_bit_cast(bf16x8, bvs[u]), accB, 0, 0, 0);
          else
            accA = __builtin_amdgcn_mfma_f32_16x16x32_bf16(av, __builtin_bit_cast(bf16x8, bvs[u]), accA, 0, 0, 0);
        }
      }
    }
    __syncthreads();   // Rs reads done before next pass overwrites
  }
  // ---- write out: D layout col=lane&15=class, row=(lane>>4)*4+r ----
  f32x4 accT = accA + accB;
  int cls = lane & 15;
  if (cls < NC) {
#pragma unroll
    for (int r = 0; r < 4; ++r) {
      int b = b0 + wv * 16 + (lane >> 4) * 4 + r;
      if (b < BTEST) out[(size_t)b * 10 + cls] = accT[r];
    }
  }
}

extern "C" void kernel_launch(void* const* d_in, const int* in_sizes, int n_in,
                              void* d_out, int out_size, void* d_ws, size_t ws_size,
                              hipStream_t stream) {
  const float* Xtr = (const float*)d_in[0];
  const float* Xte = (const float*)d_in[1];
  const float* eW1 = (const float*)d_in[2];
  const float* eb1 = (const float*)d_in[3];
  const float* g1  = (const float*)d_in[4];
  const float* bb1 = (const float*)d_in[5];
  const float* eW2 = (const float*)d_in[6];
  const float* eb2 = (const float*)d_in[7];
  const float* g2  = (const float*)d_in[8];
  const float* bb2 = (const float*)d_in[9];
  const float* hW1 = (const float*)d_in[10];
  const float* hb1 = (const float*)d_in[11];
  const float* hW2 = (const float*)d_in[12];
  const float* hb2 = (const float*)d_in[13];
  const float* tw  = (const float*)d_in[14];

  char* ws = (char*)d_ws;
  const size_t OFF_PART = 0;        // 512*128*4 = 262144 B
  const size_t OFF_Z2   = 262144;   // 2048 B
  const size_t OFF_HH   = 264192;   // 20480 B
  const size_t OFF_LEAF = 284672;   // 48000 B
  const size_t OFF_SB   = 332672;   // 1856 B
  const size_t OFF_WB   = 334528;   // 118784 B
  const size_t OFF_TOB  = 453312;   // 38912 B
  const size_t NEED     = 492224;
  if (ws_size < NEED) return;  // insufficient workspace -> fail loud (wrong output)

  float* partial = (float*)(ws + OFF_PART);
  float* z2p = (float*)(ws + OFF_Z2);
  float* hhp = (float*)(ws + OFF_HH);
  float* leafp = (float*)(ws + OFF_LEAF);
  float* sbp = (float*)(ws + OFF_SB);
  unsigned short* Wb = (unsigned short*)(ws + OFF_WB);
  unsigned short* TOBp = (unsigned short*)(ws + OFF_TOB);

  k_colsum<<<512, 256, 0, stream>>>(Xtr, partial);
  k_z2<<<128, 256, 0, stream>>>(partial, eW1, eb1, g1, bb1, eW2, eb2, z2p);
  k_hh<<<320, 256, 0, stream>>>(z2p, g2, bb2, hW1, hb1, hhp);
  k_params<<<2190, 256, 0, stream>>>(hW2, hhp, hb2, Wb, sbp, leafp);
  // ---- attribution replicas: idempotent re-runs of k_params (same inputs ->
  // identical Wb/sb/leaf). T_params = (dur - 126.6us) / 3.
  k_params<<<2190, 256, 0, stream>>>(hW2, hhp, hb2, Wb, sbp, leafp);
  k_params<<<2190, 256, 0, stream>>>(hW2, hhp, hb2, Wb, sbp, leafp);
  k_params<<<2190, 256, 0, stream>>>(hW2, hhp, hb2, Wb, sbp, leafp);
  k_tob<<<NGRP, 64, 0, stream>>>(leafp, tw, TOBp);
  k_fused<<<1563, 256, 0, stream>>>(Xte, Wb, sbp, TOBp, (float*)d_out);
}

// Round 19
// 145.047 us; speedup vs baseline: 1.5344x; 1.5344x over previous
//
#include <hip/hip_runtime.h>

#define DD 128
#define NC 10
#define NT 15
#define NCT 150
#define NCOLS 450
#define BTRAIN 100000
#define BTEST 100000
#define GROWS 70050   // 150 * 467 needed param rows
#define NGRP 38       // ceil(150/4) ct-groups of 4 (k=32 each)

typedef __attribute__((ext_vector_type(8))) __bf16 bf16x8;
typedef __attribute__((ext_vector_type(4))) float f32x4;
typedef __attribute__((ext_vector_type(8))) unsigned short u16x8;

static __device__ __forceinline__ unsigned short f2bf(float f) {
  unsigned int u = __builtin_bit_cast(unsigned int, f);
  u = (u + 0x7FFFu + ((u >> 16) & 1u)) >> 16;
  return (unsigned short)u;
}

// ---------- K1: column partial sums of X_train (512 blocks) ----------
__global__ void __launch_bounds__(256) k_colsum(const float* __restrict__ X, float* __restrict__ partial) {
  int tid = threadIdx.x;
  int gid = blockIdx.x * 256 + tid;
  int stride = gridDim.x * 256;
  float sx = 0.f, sy = 0.f, sz = 0.f, sw = 0.f;
  const float4* Xv = (const float4*)X;
  for (int i = gid; i < BTRAIN * 32; i += stride) {
    float4 v = Xv[i];
    sx += v.x; sy += v.y; sz += v.z; sw += v.w;
  }
  __shared__ float red[256][4];
  red[tid][0] = sx; red[tid][1] = sy; red[tid][2] = sz; red[tid][3] = sw;
  __syncthreads();
  for (int off = 128; off >= 32; off >>= 1) {
    if (tid < off) {
      red[tid][0] += red[tid + off][0];
      red[tid][1] += red[tid + off][1];
      red[tid][2] += red[tid + off][2];
      red[tid][3] += red[tid + off][3];
    }
    __syncthreads();
  }
  if (tid < 32) {
#pragma unroll
    for (int i = 0; i < 4; ++i)
      partial[blockIdx.x * 128 + tid * 4 + i] = red[tid][i];
  }
}

// ---------- K2: redundant {mean + L1 + LN1} per block, then 4 coalesced z2 rows ----------
__global__ void __launch_bounds__(256) k_z2(const float* __restrict__ partial,
                                            const float* __restrict__ W1, const float* __restrict__ b1,
                                            const float* __restrict__ g1, const float* __restrict__ bb1,
                                            const float* __restrict__ W2, const float* __restrict__ b2,
                                            float* __restrict__ z2g) {
  __shared__ float mS[128];
  __shared__ float redS[256];
  __shared__ float z1S[512];
  __shared__ float h1S[512];
  int tid = threadIdx.x;
  {
    int c = tid & 127, h = tid >> 7;
    float s = 0.0f;
    const float* pp = partial + (size_t)(h * 256) * 128 + c;
    for (int k = 0; k < 256; ++k) s += pp[k * 128];
    redS[tid] = s;
    __syncthreads();
    if (tid < 128) mS[tid] = (redS[tid] + redS[tid + 128]) * (1.0f / BTRAIN);
    __syncthreads();
  }
  for (int r = tid; r < 512; r += 256) {
    const float4* w = (const float4*)(W1 + (size_t)r * DD);
    float z = b1[r];
#pragma unroll
    for (int j = 0; j < 32; ++j) {
      float4 wv = w[j];
      z += wv.x * mS[4 * j] + wv.y * mS[4 * j + 1] + wv.z * mS[4 * j + 2] + wv.w * mS[4 * j + 3];
    }
    z1S[r] = z;
  }
  __syncthreads();
  {
    float a = z1S[tid], b = z1S[tid + 256];
    redS[tid] = a + b; __syncthreads();
    for (int off = 128; off > 0; off >>= 1) { if (tid < off) redS[tid] += redS[tid + off]; __syncthreads(); }
    float m = redS[0] * (1.0f / 512.0f); __syncthreads();
    float da = a - m, db = b - m;
    redS[tid] = da * da + db * db; __syncthreads();
    for (int off = 128; off > 0; off >>= 1) { if (tid < off) redS[tid] += redS[tid + off]; __syncthreads(); }
    float rs = rsqrtf(redS[0] * (1.0f / 512.0f) + 1e-5f); __syncthreads();
    h1S[tid] = fmaxf(da * rs * g1[tid] + bb1[tid], 0.0f);
    h1S[tid + 256] = fmaxf(db * rs * g1[tid + 256] + bb1[tid + 256], 0.0f);
  }
  __syncthreads();
  {
    int wv = tid >> 6, lane = tid & 63;
    int r = blockIdx.x * 4 + wv;
    const float4* wr = (const float4*)(W2 + (size_t)r * 512) + lane * 2;
    const float4* xv = (const float4*)h1S + lane * 2;
    float4 a0 = wr[0], a1 = wr[1], x0 = xv[0], x1 = xv[1];
    float s = a0.x * x0.x + a0.y * x0.y + a0.z * x0.z + a0.w * x0.w
            + a1.x * x1.x + a1.y * x1.y + a1.z * x1.z + a1.w * x1.w;
#pragma unroll
    for (int off = 32; off > 0; off >>= 1) s += __shfl_down(s, off);
    if (lane == 0) z2g[r] = s + b2[r];
  }
}

// ---------- K3: redundant LN2 per block, then 16 coalesced hh rows ----------
__global__ void __launch_bounds__(256) k_hh(const float* __restrict__ z2g,
                                            const float* __restrict__ g2, const float* __restrict__ bb2,
                                            const float* __restrict__ hW1, const float* __restrict__ hb1,
                                            float* __restrict__ hh) {
  __shared__ float redS[256];
  __shared__ float h2S[512];
  int tid = threadIdx.x;
  {
    float a = z2g[tid], b = z2g[tid + 256];
    redS[tid] = a + b; __syncthreads();
    for (int off = 128; off > 0; off >>= 1) { if (tid < off) redS[tid] += redS[tid + off]; __syncthreads(); }
    float m = redS[0] * (1.0f / 512.0f); __syncthreads();
    float da = a - m, db = b - m;
    redS[tid] = da * da + db * db; __syncthreads();
    for (int off = 128; off > 0; off >>= 1) { if (tid < off) redS[tid] += redS[tid + off]; __syncthreads(); }
    float rs = rsqrtf(redS[0] * (1.0f / 512.0f) + 1e-5f); __syncthreads();
    h2S[tid] = fmaxf(da * rs * g2[tid] + bb2[tid], 0.0f);
    h2S[tid + 256] = fmaxf(db * rs * g2[tid + 256] + bb2[tid + 256], 0.0f);
  }
  __syncthreads();
  int wv = tid >> 6, lane = tid & 63;
  const float4* xv = (const float4*)h2S + lane * 2;
  float4 x0 = xv[0], x1 = xv[1];
  float4 a[4][2];
  int r0 = blockIdx.x * 16 + wv * 4;
#pragma unroll
  for (int i = 0; i < 4; ++i) {
    const float4* wr = (const float4*)(hW1 + (size_t)(r0 + i) * 512) + lane * 2;
    a[i][0] = wr[0];
    a[i][1] = wr[1];
  }
#pragma unroll
  for (int i = 0; i < 4; ++i) {
    float s = a[i][0].x * x0.x + a[i][0].y * x0.y + a[i][0].z * x0.z + a[i][0].w * x0.w
            + a[i][1].x * x1.x + a[i][1].y * x1.y + a[i][1].z * x1.z + a[i][1].w * x1.w;
#pragma unroll
    for (int off = 32; off > 0; off >>= 1) s += __shfl_down(s, off);
    if (lane == 0) hh[r0 + i] = fmaxf(s + hb1[r0 + i], 0.0f);
  }
}

// ---------- K4: gather-matvec of needed head_W2 rows, 8 rows/wave ----------
__global__ void __launch_bounds__(256) k_params(const float* __restrict__ W2, const float* __restrict__ hh,
                                                const float* __restrict__ b2, unsigned short* __restrict__ Wb,
                                                float* __restrict__ sb, float* __restrict__ leaf) {
  int wv = threadIdx.x >> 6, lane = threadIdx.x & 63;
  int base = (blockIdx.x * 4 + wv) * 8;
  if (base >= GROWS) return;
  float4 a[8][2];
  size_t rowoff[8];
  int ctArr[8], wArr[8], cArr[8];
#pragma unroll
  for (int i = 0; i < 8; ++i) {
    int R = base + i;
    if (R >= GROWS) R = GROWS - 1;  // duplicate tail row: identical value stores, benign
    int ctIdx = R / 467;
    int w = R - ctIdx * 467;
    int c = ctIdx / 15;
    int t = ctIdx - c * 15;
    int p;
    if (w < 384) p = t * 983 + w;
    else if (w < 387) p = t * 983 + 896 + (w - 384);
    else p = t * 983 + 903 + (w - 387);
    rowoff[i] = (size_t)c * 14745 + p;
    ctArr[i] = ctIdx; wArr[i] = w; cArr[i] = c;
    const float4* wr = (const float4*)(W2 + rowoff[i] * 512) + lane * 2;
    a[i][0] = wr[0];
    a[i][1] = wr[1];
  }
#pragma unroll
  for (int i = 0; i < 8; ++i) {
    const float4* xv = (const float4*)(hh + cArr[i] * 512) + lane * 2;
    float4 x0 = xv[0], x1 = xv[1];
    float s = a[i][0].x * x0.x + a[i][0].y * x0.y + a[i][0].z * x0.z + a[i][0].w * x0.w
            + a[i][1].x * x1.x + a[i][1].y * x1.y + a[i][1].z * x1.z + a[i][1].w * x1.w;
#pragma unroll
    for (int off = 32; off > 0; off >>= 1) s += __shfl_down(s, off);
    if (lane == 0) {
      s += b2[rowoff[i]];
      int w = wArr[i], ctIdx = ctArr[i];
      if (w < 384) {
        int ii = w >> 7, d = w & 127;
        Wb[(size_t)(ctIdx * 3 + ii) * DD + d] = f2bf(s);
      } else if (w < 387) {
        sb[ctIdx * 3 + (w - 384)] = s;
      } else {
        leaf[ctIdx * 80 + (w - 387)] = s;
      }
    }
  }
}

// ---------- K5: TOB = softmax(leaf)*wt/C laid out as mfma B-fragments ----------
__global__ void k_tob(const float* __restrict__ leaf, const float* __restrict__ tw, unsigned short* __restrict__ TOB) {
  int g = blockIdx.x;          // 0..37
  int lane = threadIdx.x;      // 0..63
  int ct = g * 4 + (lane >> 4);
  int cls = lane & 15;
  float mx = tw[0];
  for (int i = 1; i < 15; ++i) mx = fmaxf(mx, tw[i]);
  float wsum = 0.0f;
  for (int i = 0; i < 15; ++i) wsum += __expf(tw[i] - mx);
  u16x8 o;
#pragma unroll
  for (int j = 0; j < 8; ++j) {
    float v = 0.0f;
    if (ct < NCT && cls < NC) {
      float wt = __expf(tw[ct % 15] - mx) / wsum;
      const float* lr = leaf + ct * 80 + j * 10;
      float m2 = lr[0];
#pragma unroll
      for (int k = 1; k < 10; ++k) m2 = fmaxf(m2, lr[k]);
      float es = 0.0f;
#pragma unroll
      for (int k = 0; k < 10; ++k) es += __expf(lr[k] - m2);
      v = __expf(lr[cls] - m2) / es * wt * (1.0f / (float)NC);
    }
    o[j] = f2bf(v);
  }
  *(u16x8*)&TOB[((size_t)g * 64 + lane) * 8] = o;
}

// ---------- K6: fused routes GEMM + sigmoid + MFMA tree-combine ----------
// A-fragments loaded DIRECTLY from X (no LDS staging): lane (m,g) rt,ks reads
// X[(b0+rt*16+m)*128 + ks*32 + g*8 .. +8] — per instruction the wave covers 16 rows
// x 128B contiguous windows, every byte consumed, each element read once per block.
__global__ void __launch_bounds__(256) k_fused(const float* __restrict__ X, const unsigned short* __restrict__ Wb,
                                               const float* __restrict__ sb, const unsigned short* __restrict__ TOB,
                                               float* __restrict__ out) {
  __shared__ _Float16 Rs[64][242];  // 30976 B; stride 484 B = 121 dw (odd) -> conflict-free col reads
  int tid = threadIdx.x;
  int b0 = blockIdx.x * 64;
  int wv = tid >> 6, lane = tid & 63;
  int m = lane & 15, g = lane >> 4;
  // ---- A-fragments (X) direct to registers ----
  bf16x8 A[4][4];
#pragma unroll
  for (int rt = 0; rt < 4; ++rt) {
    int gb = b0 + rt * 16 + m;
    const float* xr = X + (size_t)gb * DD + g * 8;
#pragma unroll
    for (int ks = 0; ks < 4; ++ks) {
      bf16x8 u;
      if (gb < BTEST) {
        float4 va = *(const float4*)(xr + ks * 32);
        float4 vb = *(const float4*)(xr + ks * 32 + 4);
        u[0] = (__bf16)va.x; u[1] = (__bf16)va.y; u[2] = (__bf16)va.z; u[3] = (__bf16)va.w;
        u[4] = (__bf16)vb.x; u[5] = (__bf16)vb.y; u[6] = (__bf16)vb.z; u[7] = (__bf16)vb.w;
      } else {
#pragma unroll
        for (int j = 0; j < 8; ++j) u[j] = (__bf16)0.0f;
      }
      A[rt][ks] = u;
    }
  }
  f32x4 accA = 0.0f, accB = 0.0f;
  int pl = wv * 16 + m;            // this wave's point row in Rs for phase C
#pragma unroll
  for (int pass = 0; pass < 2; ++pass) {
    int passBase = pass ? 240 : 0;
    // ---- phase B: MFMA routes tiles + sigmoid into Rs (Wb prefetched) ----
    {
      int tstart, tcnt;
      if (pass == 0) { tstart = wv * 4; tcnt = (wv == 3) ? 3 : 4; }
      else { tstart = 15 + ((wv < 2) ? wv * 4 : (8 + (wv - 2) * 3)); tcnt = (wv < 2) ? 4 : 3; }
      int col = tstart * 16 + m;
      u16x8 Bv[4];
#pragma unroll
      for (int ks = 0; ks < 4; ++ks)
        Bv[ks] = *(const u16x8*)&Wb[(size_t)col * DD + ks * 32 + g * 8];
      float sbv = sb[col];
      for (int it = 0; it < tcnt; ++it) {
        int pc = (it + 1 < tcnt) ? (col + 16) : col;  // clamped prefetch
        u16x8 Bn[4];
#pragma unroll
        for (int ks = 0; ks < 4; ++ks)
          Bn[ks] = *(const u16x8*)&Wb[(size_t)pc * DD + ks * 32 + g * 8];
        float sbn = sb[pc];
        f32x4 acc[4];
#pragma unroll
        for (int rt = 0; rt < 4; ++rt) acc[rt] = 0.0f;
#pragma unroll
        for (int ks = 0; ks < 4; ++ks) {
          bf16x8 Bf = __builtin_bit_cast(bf16x8, Bv[ks]);
#pragma unroll
          for (int rt = 0; rt < 4; ++rt)
            acc[rt] = __builtin_amdgcn_mfma_f32_16x16x32_bf16(A[rt][ks], Bf, acc[rt], 0, 0, 0);
        }
        int colLocal = col - passBase;
#pragma unroll
        for (int rt = 0; rt < 4; ++rt)
#pragma unroll
          for (int r = 0; r < 4; ++r) {
            float pre = acc[rt][r] + sbv;
            float e = __expf(-pre);
            float sg = __builtin_amdgcn_rcpf(1.0f + e);
            Rs[rt * 16 + g * 4 + r][colLocal] = (_Float16)sg;
          }
#pragma unroll
        for (int ks = 0; ks < 4; ++ks) Bv[ks] = Bn[ks];
        sbv = sbn;
        col += 16;
      }
    }
    __syncthreads();
    // ---- phase C: MFMA tree-combine, 4-group load batching (MLP vs latency).
    //      ct >= NCT needs no mask: TOB B-fragment is exactly 0 there. ----
    {
      int gbase = pass ? 20 : 0;
      int gn = pass ? 18 : 20;
      int ctl = g;  // lane>>4
      int nch = gn >> 2;  // full chunks of 4 (pass0: 5, pass1: 4)
      for (int ch = 0; ch < nch; ++ch) {
        int g0 = gbase + ch * 4;
        u16x8 bvs[4];
        _Float16 r0s[4], r1s[4], r2s[4];
#pragma unroll
        for (int u = 0; u < 4; ++u) {
          int gAbs = g0 + u;
          int cb = 3 * (gAbs * 4 + ctl) - passBase;
          r0s[u] = Rs[pl][cb + 0];
          r1s[u] = Rs[pl][cb + 1];
          r2s[u] = Rs[pl][cb + 2];
          bvs[u] = *(const u16x8*)&TOB[((size_t)gAbs * 64 + lane) * 8];
        }
#pragma unroll
        for (int u = 0; u < 4; ++u) {
          float l0 = (float)r0s[u], l1 = (float)r1s[u], l2 = (float)r2s[u];
          float n0 = 1.0f - l0, n1 = 1.0f - l1, n2 = 1.0f - l2;
          float p00 = l1 * l0, p01 = l1 * n0, p10 = n1 * l0, p11 = n1 * n0;
          bf16x8 av;
          av[0] = (__bf16)(l2 * p00); av[1] = (__bf16)(l2 * p01);
          av[2] = (__bf16)(l2 * p10); av[3] = (__bf16)(l2 * p11);
          av[4] = (__bf16)(n2 * p00); av[5] = (__bf16)(n2 * p01);
          av[6] = (__bf16)(n2 * p10); av[7] = (__bf16)(n2 * p11);
          if (u & 1)
            accB = __builtin_amdgcn_mfma_f32_16x16x32_bf16(av, __builtin_bit_cast(bf16x8, bvs[u]), accB, 0, 0, 0);
          else
            accA = __builtin_amdgcn_mfma_f32_16x16x32_bf16(av, __builtin_bit_cast(bf16x8, bvs[u]), accA, 0, 0, 0);
        }
      }
      if (gn & 3) {  // pass1 tail: 2 groups
        int g0 = gbase + nch * 4;
        u16x8 bvs[2];
        _Float16 r0s[2], r1s[2], r2s[2];
#pragma unroll
        for (int u = 0; u < 2; ++u) {
          int gAbs = g0 + u;
          int cb = 3 * (gAbs * 4 + ctl) - passBase;
          r0s[u] = Rs[pl][cb + 0];
          r1s[u] = Rs[pl][cb + 1];
          r2s[u] = Rs[pl][cb + 2];
          bvs[u] = *(const u16x8*)&TOB[((size_t)gAbs * 64 + lane) * 8];
        }
#pragma unroll
        for (int u = 0; u < 2; ++u) {
          float l0 = (float)r0s[u], l1 = (float)r1s[u], l2 = (float)r2s[u];
          float n0 = 1.0f - l0, n1 = 1.0f - l1, n2 = 1.0f - l2;
          float p00 = l1 * l0, p01 = l1 * n0, p10 = n1 * l0, p11 = n1 * n0;
          bf16x8 av;
          av[0] = (__bf16)(l2 * p00); av[1] = (__bf16)(l2 * p01);
          av[2] = (__bf16)(l2 * p10); av[3] = (__bf16)(l2 * p11);
          av[4] = (__bf16)(n2 * p00); av[5] = (__bf16)(n2 * p01);
          av[6] = (__bf16)(n2 * p10); av[7] = (__bf16)(n2 * p11);
          if (u & 1)
            accB = __builtin_amdgcn_mfma_f32_16x16x32_bf16(av, __builtin_bit_cast(bf16x8, bvs[u]), accB, 0, 0, 0);
          else
            accA = __builtin_amdgcn_mfma_f32_16x16x32_bf16(av, __builtin_bit_cast(bf16x8, bvs[u]), accA, 0, 0, 0);
        }
      }
    }
    __syncthreads();   // Rs reads done before next pass overwrites
  }
  // ---- write out: D layout col=lane&15=class, row=(lane>>4)*4+r ----
  f32x4 accT = accA + accB;
  int cls = lane & 15;
  if (cls < NC) {
#pragma unroll
    for (int r = 0; r < 4; ++r) {
      int b = b0 + wv * 16 + (lane >> 4) * 4 + r;
      if (b < BTEST) out[(size_t)b * 10 + cls] = accT[r];
    }
  }
}

extern "C" void kernel_launch(void* const* d_in, const int* in_sizes, int n_in,
                              void* d_out, int out_size, void* d_ws, size_t ws_size,
                              hipStream_t stream) {
  const float* Xtr = (const float*)d_in[0];
  const float* Xte = (const float*)d_in[1];
  const float* eW1 = (const float*)d_in[2];
  const float* eb1 = (const float*)d_in[3];
  const float* g1  = (const float*)d_in[4];
  const float* bb1 = (const float*)d_in[5];
  const float* eW2 = (const float*)d_in[6];
  const float* eb2 = (const float*)d_in[7];
  const float* g2  = (const float*)d_in[8];
  const float* bb2 = (const float*)d_in[9];
  const float* hW1 = (const float*)d_in[10];
  const float* hb1 = (const float*)d_in[11];
  const float* hW2 = (const float*)d_in[12];
  const float* hb2 = (const float*)d_in[13];
  const float* tw  = (const float*)d_in[14];

  char* ws = (char*)d_ws;
  const size_t OFF_PART = 0;        // 512*128*4 = 262144 B
  const size_t OFF_Z2   = 262144;   // 2048 B
  const size_t OFF_HH   = 264192;   // 20480 B
  const size_t OFF_LEAF = 284672;   // 48000 B
  const size_t OFF_SB   = 332672;   // 1856 B
  const size_t OFF_WB   = 334528;   // 118784 B
  const size_t OFF_TOB  = 453312;   // 38912 B
  const size_t NEED     = 492224;
  if (ws_size < NEED) return;  // insufficient workspace -> fail loud (wrong output)

  float* partial = (float*)(ws + OFF_PART);
  float* z2p = (float*)(ws + OFF_Z2);
  float* hhp = (float*)(ws + OFF_HH);
  float* leafp = (float*)(ws + OFF_LEAF);
  float* sbp = (float*)(ws + OFF_SB);
  unsigned short* Wb = (unsigned short*)(ws + OFF_WB);
  unsigned short* TOBp = (unsigned short*)(ws + OFF_TOB);

  k_colsum<<<512, 256, 0, stream>>>(Xtr, partial);
  k_z2<<<128, 256, 0, stream>>>(partial, eW1, eb1, g1, bb1, eW2, eb2, z2p);
  k_hh<<<320, 256, 0, stream>>>(z2p, g2, bb2, hW1, hb1, hhp);
  k_params<<<2190, 256, 0, stream>>>(hW2, hhp, hb2, Wb, sbp, leafp);
  k_tob<<<NGRP, 64, 0, stream>>>(leafp, tw, TOBp);
  k_fused<<<1563, 256, 0, stream>>>(Xte, Wb, sbp, TOBp, (float*)d_out);
}

// Round 20
// 126.483 us; speedup vs baseline: 1.7596x; 1.1468x over previous
//
#include <hip/hip_runtime.h>

#define DD 128
#define NC 10
#define NT 15
#define NCT 150
#define NCOLS 450
#define BTRAIN 100000
#define BTEST 100000
#define GROWS 70050   // 150 * 467 needed param rows
#define NGRP 38       // ceil(150/4) ct-groups of 4 (k=32 each)

typedef __attribute__((ext_vector_type(8))) __bf16 bf16x8;
typedef __attribute__((ext_vector_type(4))) float f32x4;
typedef __attribute__((ext_vector_type(8))) unsigned short u16x8;

static __device__ __forceinline__ unsigned short f2bf(float f) {
  unsigned int u = __builtin_bit_cast(unsigned int, f);
  u = (u + 0x7FFFu + ((u >> 16) & 1u)) >> 16;
  return (unsigned short)u;
}

// ---------- K1: column partial sums of X_train (512 blocks) ----------
__global__ void __launch_bounds__(256) k_colsum(const float* __restrict__ X, float* __restrict__ partial) {
  int tid = threadIdx.x;
  int gid = blockIdx.x * 256 + tid;
  int stride = gridDim.x * 256;
  float sx = 0.f, sy = 0.f, sz = 0.f, sw = 0.f;
  const float4* Xv = (const float4*)X;
  for (int i = gid; i < BTRAIN * 32; i += stride) {
    float4 v = Xv[i];
    sx += v.x; sy += v.y; sz += v.z; sw += v.w;
  }
  __shared__ float red[256][4];
  red[tid][0] = sx; red[tid][1] = sy; red[tid][2] = sz; red[tid][3] = sw;
  __syncthreads();
  for (int off = 128; off >= 32; off >>= 1) {
    if (tid < off) {
      red[tid][0] += red[tid + off][0];
      red[tid][1] += red[tid + off][1];
      red[tid][2] += red[tid + off][2];
      red[tid][3] += red[tid + off][3];
    }
    __syncthreads();
  }
  if (tid < 32) {
#pragma unroll
    for (int i = 0; i < 4; ++i)
      partial[blockIdx.x * 128 + tid * 4 + i] = red[tid][i];
  }
}

// ---------- K2: redundant {mean + L1 + LN1} per block, then 4 coalesced z2 rows ----------
__global__ void __launch_bounds__(256) k_z2(const float* __restrict__ partial,
                                            const float* __restrict__ W1, const float* __restrict__ b1,
                                            const float* __restrict__ g1, const float* __restrict__ bb1,
                                            const float* __restrict__ W2, const float* __restrict__ b2,
                                            float* __restrict__ z2g) {
  __shared__ float mS[128];
  __shared__ float redS[256];
  __shared__ float z1S[512];
  __shared__ float h1S[512];
  int tid = threadIdx.x;
  {
    int c = tid & 127, h = tid >> 7;
    float s = 0.0f;
    const float* pp = partial + (size_t)(h * 256) * 128 + c;
    for (int k = 0; k < 256; ++k) s += pp[k * 128];
    redS[tid] = s;
    __syncthreads();
    if (tid < 128) mS[tid] = (redS[tid] + redS[tid + 128]) * (1.0f / BTRAIN);
    __syncthreads();
  }
  for (int r = tid; r < 512; r += 256) {
    const float4* w = (const float4*)(W1 + (size_t)r * DD);
    float z = b1[r];
#pragma unroll
    for (int j = 0; j < 32; ++j) {
      float4 wv = w[j];
      z += wv.x * mS[4 * j] + wv.y * mS[4 * j + 1] + wv.z * mS[4 * j + 2] + wv.w * mS[4 * j + 3];
    }
    z1S[r] = z;
  }
  __syncthreads();
  {
    float a = z1S[tid], b = z1S[tid + 256];
    redS[tid] = a + b; __syncthreads();
    for (int off = 128; off > 0; off >>= 1) { if (tid < off) redS[tid] += redS[tid + off]; __syncthreads(); }
    float m = redS[0] * (1.0f / 512.0f); __syncthreads();
    float da = a - m, db = b - m;
    redS[tid] = da * da + db * db; __syncthreads();
    for (int off = 128; off > 0; off >>= 1) { if (tid < off) redS[tid] += redS[tid + off]; __syncthreads(); }
    float rs = rsqrtf(redS[0] * (1.0f / 512.0f) + 1e-5f); __syncthreads();
    h1S[tid] = fmaxf(da * rs * g1[tid] + bb1[tid], 0.0f);
    h1S[tid + 256] = fmaxf(db * rs * g1[tid + 256] + bb1[tid + 256], 0.0f);
  }
  __syncthreads();
  {
    int wv = tid >> 6, lane = tid & 63;
    int r = blockIdx.x * 4 + wv;
    const float4* wr = (const float4*)(W2 + (size_t)r * 512) + lane * 2;
    const float4* xv = (const float4*)h1S + lane * 2;
    float4 a0 = wr[0], a1 = wr[1], x0 = xv[0], x1 = xv[1];
    float s = a0.x * x0.x + a0.y * x0.y + a0.z * x0.z + a0.w * x0.w
            + a1.x * x1.x + a1.y * x1.y + a1.z * x1.z + a1.w * x1.w;
#pragma unroll
    for (int off = 32; off > 0; off >>= 1) s += __shfl_down(s, off);
    if (lane == 0) z2g[r] = s + b2[r];
  }
}

// ---------- K3: redundant LN2 per block, then 16 coalesced hh rows ----------
__global__ void __launch_bounds__(256) k_hh(const float* __restrict__ z2g,
                                            const float* __restrict__ g2, const float* __restrict__ bb2,
                                            const float* __restrict__ hW1, const float* __restrict__ hb1,
                                            float* __restrict__ hh) {
  __shared__ float redS[256];
  __shared__ float h2S[512];
  int tid = threadIdx.x;
  {
    float a = z2g[tid], b = z2g[tid + 256];
    redS[tid] = a + b; __syncthreads();
    for (int off = 128; off > 0; off >>= 1) { if (tid < off) redS[tid] += redS[tid + off]; __syncthreads(); }
    float m = redS[0] * (1.0f / 512.0f); __syncthreads();
    float da = a - m, db = b - m;
    redS[tid] = da * da + db * db; __syncthreads();
    for (int off = 128; off > 0; off >>= 1) { if (tid < off) redS[tid] += redS[tid + off]; __syncthreads(); }
    float rs = rsqrtf(redS[0] * (1.0f / 512.0f) + 1e-5f); __syncthreads();
    h2S[tid] = fmaxf(da * rs * g2[tid] + bb2[tid], 0.0f);
    h2S[tid + 256] = fmaxf(db * rs * g2[tid + 256] + bb2[tid + 256], 0.0f);
  }
  __syncthreads();
  int wv = tid >> 6, lane = tid & 63;
  const float4* xv = (const float4*)h2S + lane * 2;
  float4 x0 = xv[0], x1 = xv[1];
  float4 a[4][2];
  int r0 = blockIdx.x * 16 + wv * 4;
#pragma unroll
  for (int i = 0; i < 4; ++i) {
    const float4* wr = (const float4*)(hW1 + (size_t)(r0 + i) * 512) + lane * 2;
    a[i][0] = wr[0];
    a[i][1] = wr[1];
  }
#pragma unroll
  for (int i = 0; i < 4; ++i) {
    float s = a[i][0].x * x0.x + a[i][0].y * x0.y + a[i][0].z * x0.z + a[i][0].w * x0.w
            + a[i][1].x * x1.x + a[i][1].y * x1.y + a[i][1].z * x1.z + a[i][1].w * x1.w;
#pragma unroll
    for (int off = 32; off > 0; off >>= 1) s += __shfl_down(s, off);
    if (lane == 0) hh[r0 + i] = fmaxf(s + hb1[r0 + i], 0.0f);
  }
}

// ---------- K4: gather-matvec of needed head_W2 rows, 8 rows/wave ----------
__global__ void __launch_bounds__(256) k_params(const float* __restrict__ W2, const float* __restrict__ hh,
                                                const float* __restrict__ b2, unsigned short* __restrict__ Wb,
                                                float* __restrict__ sb, float* __restrict__ leaf) {
  int wv = threadIdx.x >> 6, lane = threadIdx.x & 63;
  int base = (blockIdx.x * 4 + wv) * 8;
  if (base >= GROWS) return;
  float4 a[8][2];
  size_t rowoff[8];
  int ctArr[8], wArr[8], cArr[8];
#pragma unroll
  for (int i = 0; i < 8; ++i) {
    int R = base + i;
    if (R >= GROWS) R = GROWS - 1;  // duplicate tail row: identical value stores, benign
    int ctIdx = R / 467;
    int w = R - ctIdx * 467;
    int c = ctIdx / 15;
    int t = ctIdx - c * 15;
    int p;
    if (w < 384) p = t * 983 + w;
    else if (w < 387) p = t * 983 + 896 + (w - 384);
    else p = t * 983 + 903 + (w - 387);
    rowoff[i] = (size_t)c * 14745 + p;
    ctArr[i] = ctIdx; wArr[i] = w; cArr[i] = c;
    const float4* wr = (const float4*)(W2 + rowoff[i] * 512) + lane * 2;
    a[i][0] = wr[0];
    a[i][1] = wr[1];
  }
#pragma unroll
  for (int i = 0; i < 8; ++i) {
    const float4* xv = (const float4*)(hh + cArr[i] * 512) + lane * 2;
    float4 x0 = xv[0], x1 = xv[1];
    float s = a[i][0].x * x0.x + a[i][0].y * x0.y + a[i][0].z * x0.z + a[i][0].w * x0.w
            + a[i][1].x * x1.x + a[i][1].y * x1.y + a[i][1].z * x1.z + a[i][1].w * x1.w;
#pragma unroll
    for (int off = 32; off > 0; off >>= 1) s += __shfl_down(s, off);
    if (lane == 0) {
      s += b2[rowoff[i]];
      int w = wArr[i], ctIdx = ctArr[i];
      if (w < 384) {
        int ii = w >> 7, d = w & 127;
        Wb[(size_t)(ctIdx * 3 + ii) * DD + d] = f2bf(s);
      } else if (w < 387) {
        sb[ctIdx * 3 + (w - 384)] = s;
      } else {
        leaf[ctIdx * 80 + (w - 387)] = s;
      }
    }
  }
}

// ---------- K5: TOB = softmax(leaf)*wt/C laid out as mfma B-fragments ----------
__global__ void k_tob(const float* __restrict__ leaf, const float* __restrict__ tw, unsigned short* __restrict__ TOB) {
  int g = blockIdx.x;          // 0..37
  int lane = threadIdx.x;      // 0..63
  int ct = g * 4 + (lane >> 4);
  int cls = lane & 15;
  float mx = tw[0];
  for (int i = 1; i < 15; ++i) mx = fmaxf(mx, tw[i]);
  float wsum = 0.0f;
  for (int i = 0; i < 15; ++i) wsum += __expf(tw[i] - mx);
  u16x8 o;
#pragma unroll
  for (int j = 0; j < 8; ++j) {
    float v = 0.0f;
    if (ct < NCT && cls < NC) {
      float wt = __expf(tw[ct % 15] - mx) / wsum;
      const float* lr = leaf + ct * 80 + j * 10;
      float m2 = lr[0];
#pragma unroll
      for (int k = 1; k < 10; ++k) m2 = fmaxf(m2, lr[k]);
      float es = 0.0f;
#pragma unroll
      for (int k = 0; k < 10; ++k) es += __expf(lr[k] - m2);
      v = __expf(lr[cls] - m2) / es * wt * (1.0f / (float)NC);
    }
    o[j] = f2bf(v);
  }
  *(u16x8*)&TOB[((size_t)g * 64 + lane) * 8] = o;
}

// ---------- K6: fused routes GEMM + sigmoid + MFMA tree-combine ----------
__global__ void __launch_bounds__(256) k_fused(const float* __restrict__ X, const unsigned short* __restrict__ Wb,
                                               const float* __restrict__ sb, const unsigned short* __restrict__ TOB,
                                               float* __restrict__ out) {
  __shared__ union {
    unsigned short Xs[64][152];   // 19456 B; stride 304 B = 76 dw -> conflict-free b128
    _Float16 Rs[64][242];         // 30976 B; stride 484 B = 121 dw (odd) -> conflict-free col reads
  } sU;
  int tid = threadIdx.x;
  int b0 = blockIdx.x * 64;
  // ---- phase A: stage X tile as bf16 (compiler emits v_cvt_pk_bf16_f32) ----
  {
    int row = tid >> 2, seg = tid & 3;
    int gb = b0 + row;
    const float4* xr = (const float4*)(X + (size_t)gb * DD) + seg * 8;
#pragma unroll
    for (int j2 = 0; j2 < 4; ++j2) {
      bf16x8 u;
      if (gb < BTEST) {
        float4 va = xr[2 * j2], vb = xr[2 * j2 + 1];
        u[0] = (__bf16)va.x; u[1] = (__bf16)va.y; u[2] = (__bf16)va.z; u[3] = (__bf16)va.w;
        u[4] = (__bf16)vb.x; u[5] = (__bf16)vb.y; u[6] = (__bf16)vb.z; u[7] = (__bf16)vb.w;
      } else {
#pragma unroll
        for (int j = 0; j < 8; ++j) u[j] = (__bf16)0.0f;
      }
      *(u16x8*)&sU.Xs[row][seg * 32 + j2 * 8] = __builtin_bit_cast(u16x8, u);
    }
  }
  __syncthreads();
  // ---- A-fragments (X) to registers; Xs dead afterwards ----
  int wv = tid >> 6, lane = tid & 63;
  int m = lane & 15, g = lane >> 4;
  bf16x8 A[4][4];
#pragma unroll
  for (int rt = 0; rt < 4; ++rt)
#pragma unroll
    for (int ks = 0; ks < 4; ++ks)
      A[rt][ks] = __builtin_bit_cast(bf16x8, *(const u16x8*)&sU.Xs[rt * 16 + m][ks * 32 + g * 8]);
  __syncthreads();
  f32x4 accA = 0.0f, accB = 0.0f;
  int pl = wv * 16 + m;            // this wave's point row in Rs for phase C
#pragma unroll
  for (int pass = 0; pass < 2; ++pass) {
    int passBase = pass ? 240 : 0;
    // ---- phase B: MFMA routes tiles + sigmoid into Rs (Wb prefetched) ----
    {
      int tstart, tcnt;
      if (pass == 0) { tstart = wv * 4; tcnt = (wv == 3) ? 3 : 4; }
      else { tstart = 15 + ((wv < 2) ? wv * 4 : (8 + (wv - 2) * 3)); tcnt = (wv < 2) ? 4 : 3; }
      int col = tstart * 16 + m;
      u16x8 Bv[4];
#pragma unroll
      for (int ks = 0; ks < 4; ++ks)
        Bv[ks] = *(const u16x8*)&Wb[(size_t)col * DD + ks * 32 + g * 8];
      float sbv = sb[col];
      for (int it = 0; it < tcnt; ++it) {
        int pc = (it + 1 < tcnt) ? (col + 16) : col;  // clamped prefetch
        u16x8 Bn[4];
#pragma unroll
        for (int ks = 0; ks < 4; ++ks)
          Bn[ks] = *(const u16x8*)&Wb[(size_t)pc * DD + ks * 32 + g * 8];
        float sbn = sb[pc];
        f32x4 acc[4];
#pragma unroll
        for (int rt = 0; rt < 4; ++rt) acc[rt] = 0.0f;
#pragma unroll
        for (int ks = 0; ks < 4; ++ks) {
          bf16x8 Bf = __builtin_bit_cast(bf16x8, Bv[ks]);
#pragma unroll
          for (int rt = 0; rt < 4; ++rt)
            acc[rt] = __builtin_amdgcn_mfma_f32_16x16x32_bf16(A[rt][ks], Bf, acc[rt], 0, 0, 0);
        }
        int colLocal = col - passBase;
#pragma unroll
        for (int rt = 0; rt < 4; ++rt)
#pragma unroll
          for (int r = 0; r < 4; ++r) {
            float pre = acc[rt][r] + sbv;
            float e = __expf(-pre);
            float sg = __builtin_amdgcn_rcpf(1.0f + e);
            sU.Rs[rt * 16 + g * 4 + r][colLocal] = (_Float16)sg;
          }
#pragma unroll
        for (int ks = 0; ks < 4; ++ks) Bv[ks] = Bn[ks];
        sbv = sbn;
        col += 16;
      }
    }
    __syncthreads();
    // ---- phase C: MFMA tree-combine, 4-group load batching (MLP vs latency).
    //      ct >= NCT needs no mask: TOB B-fragment is exactly 0 there. ----
    {
      int gbase = pass ? 20 : 0;
      int gn = pass ? 18 : 20;
      int ctl = g;  // lane>>4
      int nch = gn >> 2;  // full chunks of 4 (pass0: 5, pass1: 4)
      for (int ch = 0; ch < nch; ++ch) {
        int g0 = gbase + ch * 4;
        u16x8 bvs[4];
        _Float16 r0s[4], r1s[4], r2s[4];
#pragma unroll
        for (int u = 0; u < 4; ++u) {
          int gAbs = g0 + u;
          int cb = 3 * (gAbs * 4 + ctl) - passBase;
          r0s[u] = sU.Rs[pl][cb + 0];
          r1s[u] = sU.Rs[pl][cb + 1];
          r2s[u] = sU.Rs[pl][cb + 2];
          bvs[u] = *(const u16x8*)&TOB[((size_t)gAbs * 64 + lane) * 8];
        }
#pragma unroll
        for (int u = 0; u < 4; ++u) {
          float l0 = (float)r0s[u], l1 = (float)r1s[u], l2 = (float)r2s[u];
          float n0 = 1.0f - l0, n1 = 1.0f - l1, n2 = 1.0f - l2;
          float p00 = l1 * l0, p01 = l1 * n0, p10 = n1 * l0, p11 = n1 * n0;
          bf16x8 av;
          av[0] = (__bf16)(l2 * p00); av[1] = (__bf16)(l2 * p01);
          av[2] = (__bf16)(l2 * p10); av[3] = (__bf16)(l2 * p11);
          av[4] = (__bf16)(n2 * p00); av[5] = (__bf16)(n2 * p01);
          av[6] = (__bf16)(n2 * p10); av[7] = (__bf16)(n2 * p11);
          if (u & 1)
            accB = __builtin_amdgcn_mfma_f32_16x16x32_bf16(av, __builtin_bit_cast(bf16x8, bvs[u]), accB, 0, 0, 0);
          else
            accA = __builtin_amdgcn_mfma_f32_16x16x32_bf16(av, __builtin_bit_cast(bf16x8, bvs[u]), accA, 0, 0, 0);
        }
      }
      if (gn & 3) {  // pass1 tail: 2 groups
        int g0 = gbase + nch * 4;
        u16x8 bvs[2];
        _Float16 r0s[2], r1s[2], r2s[2];
#pragma unroll
        for (int u = 0; u < 2; ++u) {
          int gAbs = g0 + u;
          int cb = 3 * (gAbs * 4 + ctl) - passBase;
          r0s[u] = sU.Rs[pl][cb + 0];
          r1s[u] = sU.Rs[pl][cb + 1];
          r2s[u] = sU.Rs[pl][cb + 2];
          bvs[u] = *(const u16x8*)&TOB[((size_t)gAbs * 64 + lane) * 8];
        }
#pragma unroll
        for (int u = 0; u < 2; ++u) {
          float l0 = (float)r0s[u], l1 = (float)r1s[u], l2 = (float)r2s[u];
          float n0 = 1.0f - l0, n1 = 1.0f - l1, n2 = 1.0f - l2;
          float p00 = l1 * l0, p01 = l1 * n0, p10 = n1 * l0, p11 = n1 * n0;
          bf16x8 av;
          av[0] = (__bf16)(l2 * p00); av[1] = (__bf16)(l2 * p01);
          av[2] = (__bf16)(l2 * p10); av[3] = (__bf16)(l2 * p11);
          av[4] = (__bf16)(n2 * p00); av[5] = (__bf16)(n2 * p01);
          av[6] = (__bf16)(n2 * p10); av[7] = (__bf16)(n2 * p11);
          if (u & 1)
            accB = __builtin_amdgcn_mfma_f32_16x16x32_bf16(av, __builtin_bit_cast(bf16x8, bvs[u]), accB, 0, 0, 0);
          else
            accA = __builtin_amdgcn_mfma_f32_16x16x32_bf16(av, __builtin_bit_cast(bf16x8, bvs[u]), accA, 0, 0, 0);
        }
      }
    }
    __syncthreads();   // Rs reads done before next pass overwrites
  }
  // ---- write out: D layout col=lane&15=class, row=(lane>>4)*4+r ----
  f32x4 accT = accA + accB;
  int cls = lane & 15;
  if (cls < NC) {
#pragma unroll
    for (int r = 0; r < 4; ++r) {
      int b = b0 + wv * 16 + (lane >> 4) * 4 + r;
      if (b < BTEST) out[(size_t)b * 10 + cls] = accT[r];
    }
  }
}

extern "C" void kernel_launch(void* const* d_in, const int* in_sizes, int n_in,
                              void* d_out, int out_size, void* d_ws, size_t ws_size,
                              hipStream_t stream) {
  const float* Xtr = (const float*)d_in[0];
  const float* Xte = (const float*)d_in[1];
  const float* eW1 = (const float*)d_in[2];
  const float* eb1 = (const float*)d_in[3];
  const float* g1  = (const float*)d_in[4];
  const float* bb1 = (const float*)d_in[5];
  const float* eW2 = (const float*)d_in[6];
  const float* eb2 = (const float*)d_in[7];
  const float* g2  = (const float*)d_in[8];
  const float* bb2 = (const float*)d_in[9];
  const float* hW1 = (const float*)d_in[10];
  const float* hb1 = (const float*)d_in[11];
  const float* hW2 = (const float*)d_in[12];
  const float* hb2 = (const float*)d_in[13];
  const float* tw  = (const float*)d_in[14];

  char* ws = (char*)d_ws;
  const size_t OFF_PART = 0;        // 512*128*4 = 262144 B
  const size_t OFF_Z2   = 262144;   // 2048 B
  const size_t OFF_HH   = 264192;   // 20480 B
  const size_t OFF_LEAF = 284672;   // 48000 B
  const size_t OFF_SB   = 332672;   // 1856 B
  const size_t OFF_WB   = 334528;   // 118784 B
  const size_t OFF_TOB  = 453312;   // 38912 B
  const size_t NEED     = 492224;
  if (ws_size < NEED) return;  // insufficient workspace -> fail loud (wrong output)

  float* partial = (float*)(ws + OFF_PART);
  float* z2p = (float*)(ws + OFF_Z2);
  float* hhp = (float*)(ws + OFF_HH);
  float* leafp = (float*)(ws + OFF_LEAF);
  float* sbp = (float*)(ws + OFF_SB);
  unsigned short* Wb = (unsigned short*)(ws + OFF_WB);
  unsigned short* TOBp = (unsigned short*)(ws + OFF_TOB);

  k_colsum<<<512, 256, 0, stream>>>(Xtr, partial);
  k_z2<<<128, 256, 0, stream>>>(partial, eW1, eb1, g1, bb1, eW2, eb2, z2p);
  k_hh<<<320, 256, 0, stream>>>(z2p, g2, bb2, hW1, hb1, hhp);
  k_params<<<2190, 256, 0, stream>>>(hW2, hhp, hb2, Wb, sbp, leafp);
  k_tob<<<NGRP, 64, 0, stream>>>(leafp, tw, TOBp);
  k_fused<<<1563, 256, 0, stream>>>(Xte, Wb, sbp, TOBp, (float*)d_out);
}